// Round 1
// baseline (50.224 us; speedup 1.0000x reference)
//
#include <hip/hip_runtime.h>
#include <hip/hip_cooperative_groups.h>
#include <math.h>

namespace cg = cooperative_groups;

#define B 4
#define NP 4096
#define DIM 128
#define CCH 64
#define NS 8

// -------- shared-memory layout --------
// Persistent across grid.sync (block stays resident in cooperative launch):
//   fs4  : feat for this block's 16 queries (phase 2 -> phase 3)
//   sidx : ball-query indices (phase 1 -> phase 2)
// Union region is phase-exclusive.
struct TrS { float tile[128][31]; };                  // 15.9 KB, transpose staging
struct K2S { float As[16 * 132]; float red[4][14]; }; // 8.7 KB
struct K3S {                                          // 23.5 KB (largest)
  float4 vs4[256]; float4 ow4[1024];
  float cw[256], cb[64], Av[64], Bv[64], ob[64];
  float red2[8][14], Sm[14], SxA[64], SxxA[64];
};
struct SM {
  float4 fs4[128];   // 2048 B
  int sidx[128];     // 512 B
  union { TrS tr; K2S k2; K3S k3; } u;
};

// ==================== fused cooperative kernel: 1024 x 256 ====================
__global__ __launch_bounds__(256, 4) void fused_all(
    const float* __restrict__ coords, const float* __restrict__ xyz2,
    const float* __restrict__ f1, const float* __restrict__ f2,
    const float* __restrict__ conv_w, const float* __restrict__ conv_b,
    const float* __restrict__ gamma, const float* __restrict__ beta,
    const float* __restrict__ prelu, const float* __restrict__ out_w,
    const float* __restrict__ out_b, float* __restrict__ out,
    float* __restrict__ f2T, float* __restrict__ parts, int useT) {
  cg::grid_group grid = cg::this_grid();
  __shared__ SM sm;
  int blk = blockIdx.x;
  int t = threadIdx.x;
  // one (batch, chunk-of-16-queries) mapping shared by phases 1b/2/3 so
  // idx and feat can stay LDS-resident across grid.sync
  int bq = (blk & 7) >> 1;
  int chunk = ((blk >> 3) << 1) | (blk & 1);
  int m0 = chunk * 16;

  // ---------- phase 1a: f2 transpose sub-tile [128 d][16 n] ----------
  // LDS column swizzle: column n of row r stored at n + 5*(r>>5).
  // Read banks = (-4*(dg&7) + 5*(dg>>3) - c + n) mod 32: injective over dg
  // => 2-way (free). Unswizzled stride-17 layout was 4-way on all reads.
  if (useT) {
    int b = blk >> 8;
    int n0 = (blk & 255) * 16;
    const float* s = f2 + (size_t)b * DIM * NP;
    float* dd = f2T + (size_t)b * NP * DIM;
#pragma unroll
    for (int it = 0; it < 2; ++it) {
      int f = t + it * 256;
      int d = f >> 2, ng = f & 3;
      float4 v = *(const float4*)&s[(size_t)d * NP + n0 + ng * 4];
      int aw = 5 * (d >> 5);
      sm.u.tr.tile[d][ng * 4 + 0 + aw] = v.x;
      sm.u.tr.tile[d][ng * 4 + 1 + aw] = v.y;
      sm.u.tr.tile[d][ng * 4 + 2 + aw] = v.z;
      sm.u.tr.tile[d][ng * 4 + 3 + aw] = v.w;
    }
    __syncthreads();
#pragma unroll
    for (int it = 0; it < 2; ++it) {
      int f = t + it * 256;
      int n = f >> 5, dg = f & 31;
      int ar = 5 * (dg >> 3);
      float4 w;
      w.x = sm.u.tr.tile[dg * 4 + 0][n + ar];
      w.y = sm.u.tr.tile[dg * 4 + 1][n + ar];
      w.z = sm.u.tr.tile[dg * 4 + 2][n + ar];
      w.w = sm.u.tr.tile[dg * 4 + 3][n + ar];
      *(float4*)&dd[(size_t)(n0 + n) * DIM + dg * 4] = w;
    }
  }

  // ---------- phase 1b: ball query for OWN chunk, wave-per-query ----------
  // Rank-based parallel deposit replaces the serial ballot-bit while-loop.
  {
    int wv = t >> 6, lane = t & 63;
    const float* xz = xyz2 + (size_t)bq * NP * 3;
#pragma unroll 1
    for (int qi = 0; qi < 4; ++qi) {
      int m = m0 + wv * 4 + qi;
      const float* cp = coords + ((size_t)bq * NP + m) * 3;
      float cx = cp[0], cy = cp[1], cz = cp[2];
      int j0 = lane * 3;
      float px = xz[j0], py = xz[j0 + 1], pz = xz[j0 + 2];
      int cnt = 0, first = 0;
      bool any = false;
      for (int c = 0; c < 64 && cnt < NS; ++c) {
        int cn = (c < 63) ? c + 1 : 63;
        int jn = (cn * 64 + lane) * 3;
        float nx = xz[jn], ny = xz[jn + 1], nz = xz[jn + 2];
        // no-fma so the d2<1 boundary matches numpy rounding
        float dx = __fsub_rn(cx, px);
        float dy = __fsub_rn(cy, py);
        float dz = __fsub_rn(cz, pz);
        float d2 = __fadd_rn(__fadd_rn(__fmul_rn(dx, dx), __fmul_rn(dy, dy)),
                             __fmul_rn(dz, dz));
        bool hit = d2 < 1.0f;
        unsigned long long mk = __ballot(hit);
        if (mk) {
          int rank = cnt + __popcll(mk & ((1ull << lane) - 1ull));
          if (hit && rank < NS) sm.sidx[(wv * 4 + qi) * NS + rank] = c * 64 + lane;
          if (!any) {
            first = c * 64 + (__ffsll((long long)mk) - 1);
            any = true;
          }
          cnt += __popcll(mk);
        }
        px = nx; py = ny; pz = nz;
      }
      if (lane < NS && lane >= cnt)
        sm.sidx[(wv * 4 + qi) * NS + lane] = first;  // first==0 when no hit
    }
  }

  grid.sync();

  // ---------- phase 2: corr dot + feat(LDS) + moment partials ----------
  {
    K2S& k2 = sm.u.k2;
    int b = bq;
    if (useT) {
#pragma unroll
      for (int pass = 0; pass < 2; ++pass) {
        int d = pass * 64 + (t >> 2);
        int j4 = t & 3;
        float4 v = *(const float4*)&f1[(size_t)(b * DIM + d) * NP + m0 + j4 * 4];
        k2.As[(j4 * 4 + 0) * 132 + d] = v.x;
        k2.As[(j4 * 4 + 1) * 132 + d] = v.y;
        k2.As[(j4 * 4 + 2) * 132 + d] = v.z;
        k2.As[(j4 * 4 + 3) * 132 + d] = v.w;
      }
    }
    __syncthreads();

    int g = t >> 3;
    int l = t & 7;
    int idv[4];
#pragma unroll
    for (int r = 0; r < 4; ++r) idv[r] = sm.sidx[r * 32 + g];

    float pm[14];
#pragma unroll
    for (int k = 0; k < 14; ++k) pm[k] = 0.f;

#pragma unroll
    for (int r = 0; r < 4; ++r) {
      int pi = r * 32 + g;
      int m = pi >> 3;
      int id = idv[r];
      float acc = 0.f;
      if (useT) {
        const float4* brow = (const float4*)(f2T + ((size_t)b * NP + id) * DIM);
        const float4* arow = (const float4*)&k2.As[m * 132];
#pragma unroll
        for (int k = 0; k < 4; ++k) {
          float4 y = brow[l + 8 * k];
          float4 x = arow[l + 8 * k];
          acc += x.x * y.x + x.y * y.y + x.z * y.z + x.w * y.w;
        }
      } else {
#pragma unroll
        for (int k = 0; k < 4; ++k) {
#pragma unroll
          for (int c = 0; c < 4; ++c) {
            int d = (l + 8 * k) * 4 + c;
            acc += f1[(size_t)(b * DIM + d) * NP + m0 + m] *
                   f2[(size_t)(b * DIM + d) * NP + id];
          }
        }
      }
      acc += __shfl_xor(acc, 1);
      acc += __shfl_xor(acc, 2);
      acc += __shfl_xor(acc, 4);
      float corr = acc * 0.08838834764831843f;  // 1/sqrt(128)
      const float* cp = coords + ((size_t)b * NP + m0 + m) * 3;
      const float* xp = xyz2 + ((size_t)b * NP + id) * 3;
      float dx = xp[0] - cp[0], dy = xp[1] - cp[1], dz = xp[2] - cp[2];
      if (l == 0) {
        float4 fv;
        fv.x = corr; fv.y = dx; fv.z = dy; fv.w = dz;
        sm.fs4[pi] = fv;  // stays in LDS for phase 3
      }
      pm[0] += corr; pm[1] += dx; pm[2] += dy; pm[3] += dz;
      pm[4] += corr * corr; pm[5] += corr * dx; pm[6] += corr * dy;
      pm[7] += corr * dz; pm[8] += dx * dx; pm[9] += dx * dy;
      pm[10] += dx * dz; pm[11] += dy * dy; pm[12] += dy * dz; pm[13] += dz * dz;
    }
#pragma unroll
    for (int k = 0; k < 14; ++k) {
      float v = pm[k];
#pragma unroll
      for (int off = 32; off; off >>= 1) v += __shfl_xor(v, off);
      pm[k] = v;
    }
    int lane = t & 63, wvv = t >> 6;
    if (lane == 0) {
#pragma unroll
      for (int k = 0; k < 14; ++k) k2.red[wvv][k] = pm[k];
    }
    __syncthreads();
    if (t < 14) {
      float ssum = (k2.red[0][t] + k2.red[1][t] + k2.red[2][t] + k2.red[3][t]) * 0.125f;
      parts[((size_t)bq * 256 + chunk) * 14 + t] = ssum;
    }
  }

  grid.sync();

  // ---------- phase 3: stats + conv+affine+prelu+max + out GEMM ----------
  {
    K3S& kb = sm.u.k3;
    int b = bq;
    int n0 = m0;
    {
      const float4* src = (const float4*)out_w;
#pragma unroll
      for (int k = 0; k < 4; ++k) {
        int i4 = t + k * 256;
        int oo = i4 >> 4, gg = i4 & 15;
        kb.ow4[oo * 16 + (gg ^ ((oo >> 2) & 7))] = src[i4];
      }
    }
    kb.cw[t] = conv_w[t];
    if (t < 64) {
      kb.cb[t] = conv_b[t];
      kb.ob[t] = out_b[t];
    }
    if (t < 112) {
      int k = t % 14, jg = t / 14;
      float s = 0.f;
      const float* pp = parts + ((size_t)b * 256 + jg * 32) * 14 + k;
      for (int j = 0; j < 32; ++j) s += pp[j * 14];
      kb.red2[jg][k] = s;
    }
    float alpha = prelu[0];
    __syncthreads();
    if (t < 14) {
      float s = 0.f;
#pragma unroll
      for (int jg = 0; jg < 8; ++jg) s += kb.red2[jg][t];
      kb.Sm[t] = s;
    }
    __syncthreads();
    if (t < 64) {
      int o = t;
      float w0 = kb.cw[o * 4 + 0], w1 = kb.cw[o * 4 + 1];
      float w2 = kb.cw[o * 4 + 2], w3 = kb.cw[o * 4 + 3];
      float bo = kb.cb[o];
      const float cnt = (float)(NP * NS);
      float wS1 = w0 * kb.Sm[0] + w1 * kb.Sm[1] + w2 * kb.Sm[2] + w3 * kb.Sm[3];
      float q = w0 * w0 * kb.Sm[4] + w1 * w1 * kb.Sm[8] + w2 * w2 * kb.Sm[11] +
                w3 * w3 * kb.Sm[13] +
                2.f * (w0 * w1 * kb.Sm[5] + w0 * w2 * kb.Sm[6] + w0 * w3 * kb.Sm[7] +
                       w1 * w2 * kb.Sm[9] + w1 * w3 * kb.Sm[10] + w2 * w3 * kb.Sm[12]);
      kb.SxA[o] = wS1 + bo * cnt;
      kb.SxxA[o] = q + 2.f * bo * wS1 + bo * bo * cnt;
    }
    __syncthreads();
    if (t < 64) {
      int o = t, g = o >> 3;
      const float cnt = (float)(NP * NS);
      float sm_ = 0.f, s2 = 0.f;
#pragma unroll
      for (int k = 0; k < 8; ++k) {
        sm_ += kb.SxA[g * 8 + k];
        s2 += kb.SxxA[g * 8 + k];
      }
      float mean = sm_ / (cnt * 8.f);
      float e2 = s2 / (cnt * 8.f);
      float var = e2 - mean * mean;
      float inv = rsqrtf(var + 1e-5f);
      float A = gamma[o] * inv;
      kb.Av[o] = A;
      kb.Bv[o] = beta[o] - mean * A;
    }
    __syncthreads();

    {
      int o = t & 63;
      int pw = t >> 6;
      float w0 = kb.cw[o * 4 + 0], w1 = kb.cw[o * 4 + 1];
      float w2 = kb.cw[o * 4 + 2], w3 = kb.cw[o * 4 + 3];
      float A = kb.Av[o], Bc = kb.Bv[o], bb = kb.cb[o];
      float* vsf = (float*)kb.vs4;
#pragma unroll
      for (int i = 0; i < 4; ++i) {
        int p = pw * 4 + i;
        float mx = -INFINITY;
#pragma unroll
        for (int s = 0; s < NS; ++s) {
          float4 f = sm.fs4[p * 8 + s];
          float x = fmaf(w0, f.x, fmaf(w1, f.y, fmaf(w2, f.z, fmaf(w3, f.w, bb))));
          float y = fmaf(A, x, Bc);
          y = (y >= 0.f) ? y : alpha * y;
          mx = fmaxf(mx, y);
        }
        vsf[(p * 16 + ((o >> 2) ^ ((p >> 2) & 7))) * 4 + (o & 3)] = mx;
      }
    }
    __syncthreads();

    {
      int ti = t >> 3;
      int tj = t & 7;
      float acc[2][2];
#pragma unroll
      for (int oi = 0; oi < 2; ++oi)
#pragma unroll
        for (int pj = 0; pj < 2; ++pj) acc[oi][pj] = 0.f;
#pragma unroll
      for (int g = 0; g < 16; ++g) {
        float4 vv[2], ww[2];
#pragma unroll
        for (int pj = 0; pj < 2; ++pj) {
          int p = tj * 2 + pj;
          vv[pj] = kb.vs4[p * 16 + (g ^ ((p >> 2) & 7))];
        }
#pragma unroll
        for (int oi = 0; oi < 2; ++oi) {
          int oo = ti * 2 + oi;
          ww[oi] = kb.ow4[oo * 16 + (g ^ ((oo >> 2) & 7))];
        }
#pragma unroll
        for (int oi = 0; oi < 2; ++oi)
#pragma unroll
          for (int pj = 0; pj < 2; ++pj) {
            acc[oi][pj] = fmaf(ww[oi].x, vv[pj].x, acc[oi][pj]);
            acc[oi][pj] = fmaf(ww[oi].y, vv[pj].y, acc[oi][pj]);
            acc[oi][pj] = fmaf(ww[oi].z, vv[pj].z, acc[oi][pj]);
            acc[oi][pj] = fmaf(ww[oi].w, vv[pj].w, acc[oi][pj]);
          }
      }
#pragma unroll
      for (int oi = 0; oi < 2; ++oi) {
        int oo = ti * 2 + oi;
        float bb = kb.ob[oo];
        float2 r;
        r.x = acc[oi][0] + bb;
        r.y = acc[oi][1] + bb;
        *(float2*)&out[((size_t)b * CCH + oo) * NP + n0 + tj * 2] = r;
      }
    }
  }
}

// ==================== fallback 3-kernel path (R9, proven) ====================
__global__ __launch_bounds__(256) void kA_bq_transpose(
    const float* __restrict__ coords, const float* __restrict__ xyz2,
    int* __restrict__ idxb, const float* __restrict__ f2,
    float* __restrict__ o2) {
  int blk = blockIdx.x;
  int t = threadIdx.x;
  __shared__ float tile[128][33];
  if (blk < B * NP) {
    int b = blk >> 12, m = blk & (NP - 1);
    int wv = t >> 6, lane = t & 63;
    const float* cp = coords + ((size_t)b * NP + m) * 3;
    float cx = cp[0], cy = cp[1], cz = cp[2];
    const float* xz = xyz2 + (size_t)b * NP * 3;
    int base = wv * 1024;
    int j0 = (base + lane) * 3;
    float px = xz[j0], py = xz[j0 + 1], pz = xz[j0 + 2];
    int cnt = 0, myidx = 0;
    for (int c = 0; c < 16 && cnt < NS; ++c) {
      int cn = (c < 15) ? c + 1 : 15;
      int jn = (base + cn * 64 + lane) * 3;
      float nx = xz[jn], ny = xz[jn + 1], nz = xz[jn + 2];
      float dx = __fsub_rn(cx, px);
      float dy = __fsub_rn(cy, py);
      float dz = __fsub_rn(cz, pz);
      float d2 = __fadd_rn(__fadd_rn(__fmul_rn(dx, dx), __fmul_rn(dy, dy)),
                           __fmul_rn(dz, dz));
      unsigned long long mk = __ballot(d2 < 1.0f);
      while (mk && cnt < NS) {
        int bpos = __ffsll(mk) - 1;
        int jf = base + c * 64 + bpos;
        if (lane == cnt) myidx = jf;
        ++cnt;
        mk &= mk - 1;
      }
      px = nx; py = ny; pz = nz;
    }
    __shared__ int sidx[4][NS];
    __shared__ int scnt[4];
    if (lane < NS) sidx[wv][lane] = myidx;
    if (lane == 0) scnt[wv] = cnt;
    __syncthreads();
    if (t < NS) {
      int c0 = scnt[0], c1 = scnt[1], c2 = scnt[2], c3 = scnt[3];
      int total = c0 + c1 + c2 + c3;
      int v;
      if (t < c0) v = sidx[0][t];
      else if (t < c0 + c1) v = sidx[1][t - c0];
      else if (t < c0 + c1 + c2) v = sidx[2][t - c0 - c1];
      else if (t < total) v = sidx[3][t - c0 - c1 - c2];
      else v = (c0 > 0) ? sidx[0][0]
             : (c1 > 0) ? sidx[1][0]
             : (c2 > 0) ? sidx[2][0]
             : (c3 > 0) ? sidx[3][0] : 0;
      idxb[((size_t)b * NP + m) * NS + t] = v;
    }
  } else {
    int tb = blk - B * NP;
    int b = tb >> 7;
    int n0 = (tb & 127) * 32;
    const float* s = f2 + (size_t)b * DIM * NP;
    float* d = o2 + (size_t)b * NP * DIM;
    int dr = t >> 3;
    int ng = t & 7;
#pragma unroll
    for (int k = 0; k < 4; ++k) {
      int dd = dr + 32 * k;
      float4 v = *(const float4*)&s[(size_t)dd * NP + n0 + ng * 4];
      tile[dd][ng * 4 + 0] = v.x;
      tile[dd][ng * 4 + 1] = v.y;
      tile[dd][ng * 4 + 2] = v.z;
      tile[dd][ng * 4 + 3] = v.w;
    }
    __syncthreads();
    int n = t >> 3;
#pragma unroll
    for (int k = 0; k < 4; ++k) {
      int d0 = (t & 7) * 4 + 32 * k;
      float4 w;
      w.x = tile[d0 + 0][n];
      w.y = tile[d0 + 1][n];
      w.z = tile[d0 + 2][n];
      w.w = tile[d0 + 3][n];
      *(float4*)&d[(size_t)(n0 + n) * DIM + d0] = w;
    }
  }
}

__global__ __launch_bounds__(256) void k2_corrfeat(
    const float* __restrict__ f1, const float* __restrict__ f2T,
    const float* __restrict__ coords, const float* __restrict__ xyz2,
    const int* __restrict__ idxb, float* __restrict__ feat,
    float* __restrict__ parts, int trans) {
  int i = blockIdx.x;
  int b = (i & 7) >> 1;
  int chunk = ((i >> 3) << 1) | (i & 1);
  int m0 = chunk * 16;
  int t = threadIdx.x;
  __shared__ float As[16 * 132];
  __shared__ float red[4][14];
  if (trans) {
#pragma unroll
    for (int pass = 0; pass < 2; ++pass) {
      int d = pass * 64 + (t >> 2);
      int j4 = t & 3;
      float4 v = *(const float4*)&f1[(size_t)(b * DIM + d) * NP + m0 + j4 * 4];
      As[(j4 * 4 + 0) * 132 + d] = v.x;
      As[(j4 * 4 + 1) * 132 + d] = v.y;
      As[(j4 * 4 + 2) * 132 + d] = v.z;
      As[(j4 * 4 + 3) * 132 + d] = v.w;
    }
  }
  __syncthreads();
  int g = t >> 3;
  int l = t & 7;
  size_t ibase = ((size_t)b * NP + m0) * NS;
  int idv[4];
#pragma unroll
  for (int r = 0; r < 4; ++r) idv[r] = idxb[ibase + r * 32 + g];
  float pm[14];
#pragma unroll
  for (int k = 0; k < 14; ++k) pm[k] = 0.f;
#pragma unroll
  for (int r = 0; r < 4; ++r) {
    int pi = r * 32 + g;
    int m = pi >> 3, s = pi & 7;
    int id = idv[r];
    float acc = 0.f;
    if (trans) {
      const float4* brow = (const float4*)(f2T + ((size_t)b * NP + id) * DIM);
      const float4* arow = (const float4*)&As[m * 132];
#pragma unroll
      for (int k = 0; k < 4; ++k) {
        float4 y = brow[l + 8 * k];
        float4 x = arow[l + 8 * k];
        acc += x.x * y.x + x.y * y.y + x.z * y.z + x.w * y.w;
      }
    } else {
#pragma unroll
      for (int k = 0; k < 4; ++k) {
#pragma unroll
        for (int c = 0; c < 4; ++c) {
          int d = (l + 8 * k) * 4 + c;
          acc += f1[(size_t)(b * DIM + d) * NP + m0 + m] *
                 f2T[(size_t)(b * DIM + d) * NP + id];
        }
      }
    }
    acc += __shfl_xor(acc, 1);
    acc += __shfl_xor(acc, 2);
    acc += __shfl_xor(acc, 4);
    float corr = acc * 0.08838834764831843f;
    const float* cp = coords + ((size_t)b * NP + m0 + m) * 3;
    const float* xp = xyz2 + ((size_t)b * NP + id) * 3;
    float dx = xp[0] - cp[0], dy = xp[1] - cp[1], dz = xp[2] - cp[2];
    if (l == 0) {
      float4 fv;
      fv.x = corr; fv.y = dx; fv.z = dy; fv.w = dz;
      ((float4*)feat)[((size_t)b * NP + m0 + m) * NS + s] = fv;
    }
    pm[0] += corr; pm[1] += dx; pm[2] += dy; pm[3] += dz;
    pm[4] += corr * corr; pm[5] += corr * dx; pm[6] += corr * dy;
    pm[7] += corr * dz; pm[8] += dx * dx; pm[9] += dx * dy;
    pm[10] += dx * dz; pm[11] += dy * dy; pm[12] += dy * dz; pm[13] += dz * dz;
  }
#pragma unroll
  for (int k = 0; k < 14; ++k) {
    float v = pm[k];
#pragma unroll
    for (int off = 32; off; off >>= 1) v += __shfl_xor(v, off);
    pm[k] = v;
  }
  int lane = t & 63, wvv = t >> 6;
  if (lane == 0) {
#pragma unroll
    for (int k = 0; k < 14; ++k) red[wvv][k] = pm[k];
  }
  __syncthreads();
  if (t < 14) {
    float ssum = (red[0][t] + red[1][t] + red[2][t] + red[3][t]) * 0.125f;
    parts[((size_t)b * 256 + chunk) * 14 + t] = ssum;
  }
}

__global__ __launch_bounds__(256) void kB_out(
    const float* __restrict__ feat, const float* __restrict__ parts,
    const float* __restrict__ conv_w, const float* __restrict__ conv_b,
    const float* __restrict__ gamma, const float* __restrict__ beta,
    const float* __restrict__ prelu, const float* __restrict__ out_w,
    const float* __restrict__ out_b, float* __restrict__ out) {
  int b = blockIdx.x >> 8;
  int n0 = (blockIdx.x & 255) * 16;
  __shared__ float4 fs4[16 * 8];
  __shared__ float4 vs4[16 * 16];
  __shared__ float4 ow4[64 * 16];
  __shared__ float cw[256], cb_[64], Av[64], Bv[64], ob_[64];
  __shared__ float red2[8][14];
  __shared__ float Sm[14];
  __shared__ float SxA[64], SxxA[64];
  int t = threadIdx.x;
  if (t < 128) fs4[t] = ((const float4*)(feat + ((size_t)b * NP + n0) * 32))[t];
  {
    const float4* src = (const float4*)out_w;
#pragma unroll
    for (int k = 0; k < 4; ++k) {
      int i4 = t + k * 256;
      int oo = i4 >> 4, gg = i4 & 15;
      ow4[oo * 16 + (gg ^ ((oo >> 2) & 7))] = src[i4];
    }
  }
  cw[t] = conv_w[t];
  if (t < 64) {
    cb_[t] = conv_b[t];
    ob_[t] = out_b[t];
  }
  if (t < 112) {
    int k = t % 14, jg = t / 14;
    float s = 0.f;
    const float* pp = parts + ((size_t)b * 256 + jg * 32) * 14 + k;
    for (int j = 0; j < 32; ++j) s += pp[j * 14];
    red2[jg][k] = s;
  }
  float alpha = prelu[0];
  __syncthreads();
  if (t < 14) {
    float s = 0.f;
#pragma unroll
    for (int jg = 0; jg < 8; ++jg) s += red2[jg][t];
    Sm[t] = s;
  }
  __syncthreads();
  if (t < 64) {
    int o = t;
    float w0 = cw[o * 4 + 0], w1 = cw[o * 4 + 1];
    float w2 = cw[o * 4 + 2], w3 = cw[o * 4 + 3];
    float bo = cb_[o];
    const float cnt = (float)(NP * NS);
    float wS1 = w0 * Sm[0] + w1 * Sm[1] + w2 * Sm[2] + w3 * Sm[3];
    float q = w0 * w0 * Sm[4] + w1 * w1 * Sm[8] + w2 * w2 * Sm[11] +
              w3 * w3 * Sm[13] +
              2.f * (w0 * w1 * Sm[5] + w0 * w2 * Sm[6] + w0 * w3 * Sm[7] +
                     w1 * w2 * Sm[9] + w1 * w3 * Sm[10] + w2 * w3 * Sm[12]);
    SxA[o] = wS1 + bo * cnt;
    SxxA[o] = q + 2.f * bo * wS1 + bo * bo * cnt;
  }
  __syncthreads();
  if (t < 64) {
    int o = t, g = o >> 3;
    const float cnt = (float)(NP * NS);
    float sm = 0.f, s2 = 0.f;
#pragma unroll
    for (int k = 0; k < 8; ++k) {
      sm += SxA[g * 8 + k];
      s2 += SxxA[g * 8 + k];
    }
    float mean = sm / (cnt * 8.f);
    float e2 = s2 / (cnt * 8.f);
    float var = e2 - mean * mean;
    float inv = rsqrtf(var + 1e-5f);
    float A = gamma[o] * inv;
    Av[o] = A;
    Bv[o] = beta[o] - mean * A;
  }
  __syncthreads();
  {
    int o = t & 63;
    int pw = t >> 6;
    float w0 = cw[o * 4 + 0], w1 = cw[o * 4 + 1];
    float w2 = cw[o * 4 + 2], w3 = cw[o * 4 + 3];
    float A = Av[o], Bc = Bv[o], bb = cb_[o];
    float* vsf = (float*)vs4;
#pragma unroll
    for (int i = 0; i < 4; ++i) {
      int p = pw * 4 + i;
      float mx = -INFINITY;
#pragma unroll
      for (int s = 0; s < NS; ++s) {
        float4 f = fs4[p * 8 + s];
        float x = fmaf(w0, f.x, fmaf(w1, f.y, fmaf(w2, f.z, fmaf(w3, f.w, bb))));
        float y = fmaf(A, x, Bc);
        y = (y >= 0.f) ? y : alpha * y;
        mx = fmaxf(mx, y);
      }
      vsf[(p * 16 + ((o >> 2) ^ ((p >> 2) & 7))) * 4 + (o & 3)] = mx;
    }
  }
  __syncthreads();
  {
    int ti = t >> 3;
    int tj = t & 7;
    float acc[2][2];
#pragma unroll
    for (int oi = 0; oi < 2; ++oi)
#pragma unroll
      for (int pj = 0; pj < 2; ++pj) acc[oi][pj] = 0.f;
#pragma unroll
    for (int g = 0; g < 16; ++g) {
      float4 vv[2], ww[2];
#pragma unroll
      for (int pj = 0; pj < 2; ++pj) {
        int p = tj * 2 + pj;
        vv[pj] = vs4[p * 16 + (g ^ ((p >> 2) & 7))];
      }
#pragma unroll
      for (int oi = 0; oi < 2; ++oi) {
        int oo = ti * 2 + oi;
        ww[oi] = ow4[oo * 16 + (g ^ ((oo >> 2) & 7))];
      }
#pragma unroll
      for (int oi = 0; oi < 2; ++oi)
#pragma unroll
        for (int pj = 0; pj < 2; ++pj) {
          acc[oi][pj] = fmaf(ww[oi].x, vv[pj].x, acc[oi][pj]);
          acc[oi][pj] = fmaf(ww[oi].y, vv[pj].y, acc[oi][pj]);
          acc[oi][pj] = fmaf(ww[oi].z, vv[pj].z, acc[oi][pj]);
          acc[oi][pj] = fmaf(ww[oi].w, vv[pj].w, acc[oi][pj]);
        }
    }
#pragma unroll
    for (int oi = 0; oi < 2; ++oi) {
      int oo = ti * 2 + oi;
      float bb = ob_[oo];
      float2 r;
      r.x = acc[oi][0] + bb;
      r.y = acc[oi][1] + bb;
      *(float2*)&out[((size_t)b * CCH + oo) * NP + n0 + tj * 2] = r;
    }
  }
}

extern "C" void kernel_launch(void* const* d_in, const int* in_sizes, int n_in,
                              void* d_out, int out_size, void* d_ws, size_t ws_size,
                              hipStream_t stream) {
  const float* coords = (const float*)d_in[0];
  const float* xyz2 = (const float*)d_in[1];
  const float* fmap1 = (const float*)d_in[2];
  const float* fmap2 = (const float*)d_in[3];
  const float* conv_w = (const float*)d_in[4];
  const float* conv_b = (const float*)d_in[5];
  const float* gamma = (const float*)d_in[6];
  const float* beta = (const float*)d_in[7];
  const float* prelu = (const float*)d_in[8];
  const float* out_w = (const float*)d_in[9];
  const float* out_b = (const float*)d_in[10];
  float* out = (float*)d_out;
  float* ws = (float*)d_ws;

  const size_t BND = (size_t)B * NP * DIM;
  const size_t FEAT = (size_t)B * NP * NS * 4;
  const size_t PARTS = (size_t)B * 256 * 14;
  size_t needT = (BND + FEAT + PARTS + 512) * sizeof(float) +
                 (size_t)B * NP * NS * sizeof(int);
  int useT = (ws_size >= needT) ? 1 : 0;

  float* f2T = ws;
  float* featp = useT ? (f2T + BND) : ws;
  float* parts = featp + FEAT;
  int* idxp = (int*)(parts + PARTS + 512);

  // Try single cooperative launch (1024 blocks must be fully co-resident).
  int maxBlocks = 0;
  hipError_t oe = hipOccupancyMaxActiveBlocksPerMultiprocessor(
      &maxBlocks, fused_all, 256, 0);
  if (oe == hipSuccess && maxBlocks >= 4) {
    void* args[] = {(void*)&coords, (void*)&xyz2,   (void*)&fmap1,
                    (void*)&fmap2,  (void*)&conv_w, (void*)&conv_b,
                    (void*)&gamma,  (void*)&beta,   (void*)&prelu,
                    (void*)&out_w,  (void*)&out_b,  (void*)&out,
                    (void*)&f2T,    (void*)&parts,  (void*)&useT};
    hipError_t le = hipLaunchCooperativeKernel(
        fused_all, dim3(1024), dim3(256), args, 0, stream);
    if (le == hipSuccess) return;
  }

  // Fallback: proven 3-kernel path.
  int nblk = B * NP + (useT ? (B * (NP / 32)) : 0);
  kA_bq_transpose<<<dim3(nblk), dim3(256), 0, stream>>>(coords, xyz2, idxp,
                                                        fmap2, f2T);
  k2_corrfeat<<<dim3(1024), dim3(256), 0, stream>>>(
      fmap1, useT ? f2T : fmap2, coords, xyz2, idxp, featp, parts, useT);
  kB_out<<<dim3(B * (NP / 16)), dim3(256), 0, stream>>>(
      featp, parts, conv_w, conv_b, gamma, beta, prelu, out_w, out_b, out);
}